// Round 1
// baseline (560.557 us; speedup 1.0000x reference)
//
#include <hip/hip_runtime.h>
#include <stdint.h>

#define TPB 256

// d_ws layout (32-bit words from base)
#define WS_W1F   0      // 480 floats: binarized w1 as +/-1.0f, [6][80] (75 used, 5 pad)
#define WS_W2PK  480    // 80 u32:  w2 bits, [16 oc][5 kr], bit (5c+k)
#define WS_WF1P  560    // 3000 u32: wf1 bits, [120 o][25 pos], bit oc
#define WS_WF2PK 3560   // 336 u32: wf2 bits, [84 o][4 q], bit = neuron q*32+b
#define WS_WF3PK 3896   // 30 u32:  wf3 bits, [10 o][3 q]

__global__ __launch_bounds__(TPB) void prep_kernel(
    const float* __restrict__ w1, const float* __restrict__ w2,
    const float* __restrict__ wf1, const float* __restrict__ wf2,
    const float* __restrict__ wf3, float* __restrict__ wsf,
    uint32_t* __restrict__ wsu)
{
  int id = blockIdx.x * TPB + threadIdx.x;
  if (id < 480) {
    int c = id / 80, i = id % 80;
    wsf[WS_W1F + id] = (i < 75) ? ((w1[c*75 + i] >= 0.f) ? 1.f : -1.f) : 0.f;
  } else if (id < 560) {
    int r = id - 480, oc = r / 5, kr = r % 5;
    uint32_t w = 0;
    for (int c = 0; c < 6; ++c)
      for (int k = 0; k < 5; ++k)
        w |= (uint32_t)(w2[((oc*6 + c)*5 + kr)*5 + k] >= 0.f) << (5*c + k);
    wsu[WS_W2PK + r] = w;
  } else if (id < 3560) {
    int r = id - 560, o = r / 25, p = r % 25;
    uint32_t w = 0;
    for (int oc = 0; oc < 16; ++oc)
      w |= (uint32_t)(wf1[o*400 + oc*25 + p] >= 0.f) << oc;
    wsu[WS_WF1P + r] = w;
  } else if (id < 3896) {
    int r = id - 3560, o = r / 4, q = r % 4;
    uint32_t w = 0;
    for (int b = 0; b < 32; ++b) {
      int n = q*32 + b;
      if (n < 120) w |= (uint32_t)(wf2[o*120 + n] >= 0.f) << b;
    }
    wsu[WS_WF2PK + r] = w;
  } else if (id < 3926) {
    int r = id - 3896, o = r / 3, q = r % 3;
    uint32_t w = 0;
    for (int b = 0; b < 32; ++b) {
      int n = q*32 + b;
      if (n < 84) w |= (uint32_t)(wf3[o*84 + n] >= 0.f) << b;
    }
    wsu[WS_WF3PK + r] = w;
  }
}

// Fused per-2-image pipeline: conv1(fp32) -> bits -> conv2(popcnt) -> fc1/2/3(popcnt)
__global__ __launch_bounds__(TPB) void lenet_kernel(
    const float* __restrict__ x,
    const float* __restrict__ b1, const float* __restrict__ b2,
    const float* __restrict__ bf1, const float* __restrict__ bf2,
    const float* __restrict__ bf3,
    const float* __restrict__ wsf, const uint32_t* __restrict__ wsu,
    float* __restrict__ out)
{
  // image buffer overlaid with conv2 scratch (image is dead after conv1)
  __shared__ union Ovl {
    float img[2][3][32][32];                                        // 24576 B
    struct { uint32_t ppatch[2][10][10][5]; uint8_t dbuf[2][16][10][10]; } c2; // 7200 B
  } ovl;
  __shared__ uint32_t bits1[2][6][14];   // pooled-binarized layer1: bit pj of row pi
  __shared__ uint32_t w2pks[16][5];
  __shared__ uint32_t bits2[2][25];      // bit oc per pooled pos
  __shared__ uint32_t wf2pks[84][4];
  __shared__ uint32_t wf3pks[10][3];
  __shared__ uint32_t bitsf1[2][4];
  __shared__ uint32_t bitsf2[2][3];

  const int t = threadIdx.x;
  const long long img0 = (long long)blockIdx.x * 2;

  // ---------- load phase ----------
  {
    const float4* src = (const float4*)(x + img0 * 3072);
    float4* dst = (float4*)ovl.img;
#pragma unroll
    for (int k = 0; k < 6; ++k) dst[k*TPB + t] = src[k*TPB + t];
    if (t < 80) w2pks[t/5][t%5] = wsu[WS_W2PK + t];
    if (t < 168) {
      ((uint32_t*)wf2pks)[t]       = wsu[WS_WF2PK + t];
      ((uint32_t*)wf2pks)[t + 168] = wsu[WS_WF2PK + t + 168];
      ((uint32_t*)bits1)[t] = 0;
    }
    if (t < 30) ((uint32_t*)wf3pks)[t] = wsu[WS_WF3PK + t];
    if (t < 50) ((uint32_t*)bits2)[t] = 0;
    if (t < 8)  ((uint32_t*)bitsf1)[t] = 0;
    if (t < 6)  ((uint32_t*)bitsf2)[t] = 0;
  }
  __syncthreads();

  // ---------- conv1: fp32, register-tiled, 4 pooled cols per unit ----------
  {
    const int c   = t % 6;                 // output channel (weights reused across units)
    const int tpc = t / 6;
    const int nth = (c < 4) ? 43 : 42;     // threads owning this channel
    float wreg[80];
    const float4* wp = (const float4*)(wsf + WS_W1F + c*80);
#pragma unroll
    for (int q = 0; q < 20; ++q) {
      float4 v = wp[q];
      wreg[4*q+0] = v.x; wreg[4*q+1] = v.y; wreg[4*q+2] = v.z; wreg[4*q+3] = v.w;
    }
    const float bc = b1[c];
    for (int s = tpc; s < 112; s += nth) { // 112 units per channel (2 img * 14 pi * 4 g)
      const int img2 = s / 56;
      const int rem  = s % 56;
      const int pi   = rem >> 2;
      const int g    = rem & 3;            // group of 4 pooled cols
      float acc[2][8];
#pragma unroll
      for (int dr = 0; dr < 2; ++dr)
#pragma unroll
        for (int m = 0; m < 8; ++m) acc[dr][m] = 0.f;
#pragma unroll
      for (int ic = 0; ic < 3; ++ic) {
#pragma unroll
        for (int r = 0; r < 6; ++r) {
          const float* rowp = &ovl.img[img2][ic][2*pi + r][8*g];
          float xr[12];
          float4 v0 = *(const float4*)(rowp);
          float4 v1 = *(const float4*)(rowp + 4);
          xr[0]=v0.x; xr[1]=v0.y; xr[2]=v0.z; xr[3]=v0.w;
          xr[4]=v1.x; xr[5]=v1.y; xr[6]=v1.z; xr[7]=v1.w;
          if (g < 3) {
            float4 v2 = *(const float4*)(rowp + 8);
            xr[8]=v2.x; xr[9]=v2.y; xr[10]=v2.z; xr[11]=v2.w;
          } else {
            xr[8]=0.f; xr[9]=0.f; xr[10]=0.f; xr[11]=0.f;
          }
#pragma unroll
          for (int dr = 0; dr < 2; ++dr) {
            const int kr = r - dr;
            if (kr < 0 || kr > 4) continue;  // compile-time pruned
#pragma unroll
            for (int k = 0; k < 5; ++k) {
              const float w = wreg[ic*25 + kr*5 + k];
#pragma unroll
              for (int m = 0; m < 8; ++m)
                acc[dr][m] = fmaf(xr[m + k], w, acc[dr][m]);
            }
          }
        }
      }
      uint32_t nib = 0;
#pragma unroll
      for (int jj = 0; jj < 4; ++jj) {
        const int pj = 4*g + jj;
        if (pj < 14) {
          float v = fmaxf(fmaxf(acc[0][2*jj], acc[0][2*jj+1]),
                          fmaxf(acc[1][2*jj], acc[1][2*jj+1]));
          float m = v + bc;
          if (fabsf(m) < 1e-2f) {
            // borderline: resolve sign exactly in fp64 (rare; weights from global
            // to keep wreg statically indexed / in registers)
            double best = -1e300;
            for (int dr = 0; dr < 2; ++dr)
              for (int dc = 0; dc < 2; ++dc) {
                double sacc = 0.0;
                const int cr = 2*pi + dr;
                const int cc = 8*g + 2*jj + dc;
                for (int ic2 = 0; ic2 < 3; ++ic2)
                  for (int kr2 = 0; kr2 < 5; ++kr2)
                    for (int k2 = 0; k2 < 5; ++k2)
                      sacc += (double)ovl.img[img2][ic2][cr + kr2][cc + k2] *
                              (double)wsf[WS_W1F + c*80 + ic2*25 + kr2*5 + k2];
                best = best > sacc ? best : sacc;
              }
            if (best + (double)bc >= 0.0) nib |= 1u << pj;
          } else if (m >= 0.f) {
            nib |= 1u << pj;
          }
        }
      }
      if (nib) atomicOr(&bits1[img2][c][pi], nib);
    }
  }
  __syncthreads();

  // ---------- conv2 phase A: pack 30-bit input words per (i,j,kr) ----------
  for (int id = t; id < 1000; id += TPB) {
    const int img2 = id / 500;
    const int rem  = id % 500;
    const int kr = rem % 5;
    const int ij = rem / 5;
    const int i = ij / 10, j = ij % 10;
    uint32_t w = 0;
#pragma unroll
    for (int c = 0; c < 6; ++c)
      w |= ((bits1[img2][c][i + kr] >> j) & 31u) << (5*c);
    ovl.c2.ppatch[img2][i][j][kr] = w;
  }
  __syncthreads();

  // ---------- conv2 phase B: popcount diffs ----------
  for (int id = t; id < 3200; id += TPB) {
    const int img2 = id / 1600;
    const int rem  = id % 1600;
    const int oc = rem / 100;
    const int ij = rem % 100;
    const int i = ij / 10, j = ij % 10;
    int d = 0;
#pragma unroll
    for (int kr = 0; kr < 5; ++kr)
      d += __popc(ovl.c2.ppatch[img2][i][j][kr] ^ w2pks[oc][kr]);
    ovl.c2.dbuf[img2][oc][i][j] = (uint8_t)d;  // s = 150 - 2d
  }
  __syncthreads();

  // ---------- conv2 phase C: maxpool + bias + binarize ----------
  for (int id = t; id < 800; id += TPB) {
    const int img2 = id / 400;
    const int rem  = id % 400;
    const int oc  = rem / 25;
    const int pos = rem % 25;
    const int pi = pos / 5, pj = pos % 5;
    const uint8_t* dp = &ovl.c2.dbuf[img2][oc][2*pi][2*pj];
    int d0 = dp[0], d1 = dp[1], d2 = dp[10], d3 = dp[11];
    int dmin = min(min(d0, d1), min(d2, d3));
    float v = (float)(150 - 2*dmin) + b2[oc];
    if (v >= 0.f) atomicOr(&bits2[img2][pos], 1u << oc);
  }
  __syncthreads();

  // ---------- fc1 ----------
  for (int id = t; id < 240; id += TPB) {
    const int img2 = id / 120;
    const int o = id % 120;
    const uint32_t* wrow = wsu + WS_WF1P + o*25;
    int d = 0;
#pragma unroll
    for (int p = 0; p < 25; ++p) d += __popc(bits2[img2][p] ^ wrow[p]);
    float v = (float)(400 - 2*d) + bf1[o];
    if (v >= 0.f) atomicOr(&bitsf1[img2][o >> 5], 1u << (o & 31));
  }
  __syncthreads();

  // ---------- fc2 ----------
  for (int id = t; id < 168; id += TPB) {
    const int img2 = id / 84;
    const int o = id % 84;
    int d = 0;
#pragma unroll
    for (int q = 0; q < 4; ++q) d += __popc(bitsf1[img2][q] ^ wf2pks[o][q]);
    float v = (float)(120 - 2*d) + bf2[o];
    if (v >= 0.f) atomicOr(&bitsf2[img2][o >> 5], 1u << (o & 31));
  }
  __syncthreads();

  // ---------- fc3 ----------
  for (int id = t; id < 20; id += TPB) {
    const int img2 = id / 10;
    const int o = id % 10;
    int d = 0;
#pragma unroll
    for (int q = 0; q < 3; ++q) d += __popc(bitsf2[img2][q] ^ wf3pks[o][q]);
    out[(img0 + img2)*10 + o] = (float)(84 - 2*d) + bf3[o];
  }
}

extern "C" void kernel_launch(void* const* d_in, const int* in_sizes, int n_in,
                              void* d_out, int out_size, void* d_ws, size_t ws_size,
                              hipStream_t stream)
{
  const float* x   = (const float*)d_in[0];
  const float* w1  = (const float*)d_in[1];
  const float* b1  = (const float*)d_in[2];
  const float* w2  = (const float*)d_in[3];
  const float* b2  = (const float*)d_in[4];
  const float* wf1 = (const float*)d_in[5];
  const float* bf1 = (const float*)d_in[6];
  const float* wf2 = (const float*)d_in[7];
  const float* bf2 = (const float*)d_in[8];
  const float* wf3 = (const float*)d_in[9];
  const float* bf3 = (const float*)d_in[10];
  float*    wsf = (float*)d_ws;
  uint32_t* wsu = (uint32_t*)d_ws;

  hipLaunchKernelGGL(prep_kernel, dim3(16), dim3(TPB), 0, stream,
                     w1, w2, wf1, wf2, wf3, wsf, wsu);
  hipLaunchKernelGGL(lenet_kernel, dim3(4096), dim3(TPB), 0, stream,
                     x, b1, b2, bf1, bf2, bf3, wsf, wsu, (float*)d_out);
}

// Round 2
// 210.484 us; speedup vs baseline: 2.6632x; 2.6632x over previous
//
#include <hip/hip_runtime.h>
#include <stdint.h>

#define TPB 256

// d_ws layout (32-bit words from base)
#define WS_W1F   0      // 504 floats: binarized w1 as +/-1.0f, [6][3][28] (25 used per ic, 3 pad)
#define WS_W2PK  504    // 80 u32:  w2 bits, [16 oc][5 kr], bit (5c+k)
#define WS_WF1P  584    // 3000 u32: wf1 bits, [120 o][25 pos], bit oc
#define WS_WF2PK 3584   // 336 u32: wf2 bits, [84 o][4 q], bit = neuron q*32+b
#define WS_WF3PK 3920   // 30 u32:  wf3 bits, [10 o][3 q]

__global__ __launch_bounds__(TPB) void prep_kernel(
    const float* __restrict__ w1, const float* __restrict__ w2,
    const float* __restrict__ wf1, const float* __restrict__ wf2,
    const float* __restrict__ wf3, float* __restrict__ wsf,
    uint32_t* __restrict__ wsu)
{
  int id = blockIdx.x * TPB + threadIdx.x;
  if (id < 504) {
    int c = id / 84, r = id % 84, ic = r / 28, k = r % 28;
    wsf[WS_W1F + id] = (k < 25) ? ((w1[c*75 + ic*25 + k] >= 0.f) ? 1.f : -1.f) : 0.f;
  } else if (id < 584) {
    int r = id - 504, oc = r / 5, kr = r % 5;
    uint32_t w = 0;
    for (int c = 0; c < 6; ++c)
      for (int k = 0; k < 5; ++k)
        w |= (uint32_t)(w2[((oc*6 + c)*5 + kr)*5 + k] >= 0.f) << (5*c + k);
    wsu[WS_W2PK + r] = w;
  } else if (id < 3584) {
    int r = id - 584, o = r / 25, p = r % 25;
    uint32_t w = 0;
    for (int oc = 0; oc < 16; ++oc)
      w |= (uint32_t)(wf1[o*400 + oc*25 + p] >= 0.f) << oc;
    wsu[WS_WF1P + r] = w;
  } else if (id < 3920) {
    int r = id - 3584, o = r / 4, q = r % 4;
    uint32_t w = 0;
    for (int b = 0; b < 32; ++b) {
      int n = q*32 + b;
      if (n < 120) w |= (uint32_t)(wf2[o*120 + n] >= 0.f) << b;
    }
    wsu[WS_WF2PK + r] = w;
  } else if (id < 3950) {
    int r = id - 3920, o = r / 3, q = r % 3;
    uint32_t w = 0;
    for (int b = 0; b < 32; ++b) {
      int n = q*32 + b;
      if (n < 84) w |= (uint32_t)(wf3[o*84 + n] >= 0.f) << b;
    }
    wsu[WS_WF3PK + r] = w;
  }
}

// image plane layout: rows padded to 36 floats, 16B chunks XOR-swizzled by (row>>1)&3
// to spread conv1 ds_read_b128 bank starts. Store and all reads use IMG_IDX.
__device__ __forceinline__ int IMG_IDX(int plane, int row, int colf) {
  int idx = plane * 1152 + row * 36 + colf;
  return idx ^ (((row >> 1) & 3) << 2);
}

// Fused per-2-image pipeline: conv1(fp32) -> exact-sign resolve -> conv2(popcnt) -> fc1/2/3
__global__ __launch_bounds__(TPB, 4) void lenet_kernel(
    const float* __restrict__ x,
    const float* __restrict__ b1, const float* __restrict__ b2,
    const float* __restrict__ bf1, const float* __restrict__ bf2,
    const float* __restrict__ bf3,
    const float* __restrict__ wsf, const uint32_t* __restrict__ wsu,
    float* __restrict__ out)
{
  // image buffer overlaid with conv2 scratch (image is dead after resolve pass)
  __shared__ union Ovl {
    float img[6912];                                                // 2 img * 3 c * 32 rows * 36 = 27648 B
    struct { uint32_t ppatch[2][10][10][5]; uint8_t dbuf[2][16][10][10]; } c2; // 7200 B
  } ovl;
  __shared__ float wsm[504];             // binarized conv1 weights [6][3][28]
  __shared__ float sb1[6];
  __shared__ uint32_t bits1[2][6][14];   // pooled-binarized layer1: bit pj of pooled row pi
  __shared__ uint32_t border[2][6][14];  // borderline mask (needs exact fp64 arbitration)
  __shared__ uint32_t w2pks[16][5];
  __shared__ uint32_t bits2[2][25];      // bit oc per pooled pos
  __shared__ uint32_t wf2pks[84][4];
  __shared__ uint32_t wf3pks[10][3];
  __shared__ uint32_t bitsf1[2][4];
  __shared__ uint32_t bitsf2[2][3];

  const int t = threadIdx.x;
  const long long img0 = (long long)blockIdx.x * 2;

  // ---------- load phase ----------
  {
    const float4* src = (const float4*)(x + img0 * 3072);
#pragma unroll
    for (int k = 0; k < 6; ++k) {
      int id = k*TPB + t;              // 0..1535 : plane(6) x row(32) x f4col(8)
      int plane = id >> 8, rq = id & 255, row = rq >> 3, q = rq & 7;
      *(float4*)&ovl.img[IMG_IDX(plane, row, 4*q)] = src[id];
    }
    for (int id = t; id < 504; id += TPB) wsm[id] = wsf[WS_W1F + id];
    if (t < 6)  sb1[t] = b1[t];
    if (t < 80) w2pks[t/5][t%5] = wsu[WS_W2PK + t];
    if (t < 168) {
      ((uint32_t*)wf2pks)[t]       = wsu[WS_WF2PK + t];
      ((uint32_t*)wf2pks)[t + 168] = wsu[WS_WF2PK + t + 168];
      ((uint32_t*)bits1)[t]  = 0;
      ((uint32_t*)border)[t] = 0;
    }
    if (t < 30) ((uint32_t*)wf3pks)[t] = wsu[WS_WF3PK + t];
    if (t < 50) ((uint32_t*)bits2)[t] = 0;
    if (t < 8)  ((uint32_t*)bitsf1)[t] = 0;
    if (t < 6)  ((uint32_t*)bitsf2)[t] = 0;
  }
  __syncthreads();

  // ---------- conv1: fp32, ic-outer (25 weights live), 4 pooled cols per unit ----------
  for (int u = t; u < 672; u += TPB) {     // 2 img * 6 c * 14 pi * 4 g
    const int img2 = u / 336;
    int rem = u - img2*336;
    const int c = rem / 56; rem -= c*56;
    const int pi = rem >> 2, g = rem & 3;
    const int colf = 8*g;
    float acc[2][8];
#pragma unroll
    for (int dr = 0; dr < 2; ++dr)
#pragma unroll
      for (int m = 0; m < 8; ++m) acc[dr][m] = 0.f;

#pragma unroll 1
    for (int ic = 0; ic < 3; ++ic) {
      float wr[28];
      const float4* wp = (const float4*)&wsm[c*84 + ic*28];
#pragma unroll
      for (int q2 = 0; q2 < 7; ++q2) {
        float4 v = wp[q2];
        wr[4*q2+0] = v.x; wr[4*q2+1] = v.y; wr[4*q2+2] = v.z; wr[4*q2+3] = v.w;
      }
      const int plane = img2*3 + ic;
#pragma unroll
      for (int r = 0; r < 6; ++r) {
        const int row = 2*pi + r;
        float xr[12];
        float4 v0 = *(const float4*)&ovl.img[IMG_IDX(plane, row, colf)];
        float4 v1 = *(const float4*)&ovl.img[IMG_IDX(plane, row, colf + 4)];
        float4 v2 = *(const float4*)&ovl.img[IMG_IDX(plane, row, colf + 8)]; // g=3: pad garbage, only feeds discarded acc slots
        xr[0]=v0.x; xr[1]=v0.y; xr[2]=v0.z; xr[3]=v0.w;
        xr[4]=v1.x; xr[5]=v1.y; xr[6]=v1.z; xr[7]=v1.w;
        xr[8]=v2.x; xr[9]=v2.y; xr[10]=v2.z; xr[11]=v2.w;
#pragma unroll
        for (int dr = 0; dr < 2; ++dr) {
          const int kr = r - dr;
          if (kr < 0 || kr > 4) continue;   // compile-time pruned
#pragma unroll
          for (int k = 0; k < 5; ++k) {
            const float w = wr[kr*5 + k];
#pragma unroll
            for (int m = 0; m < 8; ++m)
              acc[dr][m] = fmaf(xr[m + k], w, acc[dr][m]);
          }
        }
      }
    }

    const float bc = sb1[c];
    uint32_t nib = 0, nbord = 0;
#pragma unroll
    for (int jj = 0; jj < 4; ++jj) {
      const int pj = 4*g + jj;
      if (pj < 14) {                        // g=3: jj 2,3 discarded (only garbage accs)
        float v = fmaxf(fmaxf(acc[0][2*jj], acc[0][2*jj+1]),
                        fmaxf(acc[1][2*jj], acc[1][2*jj+1]));
        float m = v + bc;
        if (fabsf(m) < 4e-3f)  nbord |= 1u << pj;   // fp32 worst-case err ~3e-4
        else if (m >= 0.f)     nib   |= 1u << pj;
      }
    }
    if (nib)   atomicOr(&bits1[img2][c][pi], nib);
    if (nbord) atomicOr(&border[img2][c][pi], nbord);
  }
  __syncthreads();

  // ---------- borderline resolve: exact fp64 sign (rare; ~1-2 units per block) ----------
  for (int id = t; id < 2352; id += TPB) {  // 2 img * 6 c * 14 * 14
    const int img2 = id / 1176;
    int rem = id - img2*1176;
    const int c = rem / 196; rem -= c*196;
    const int pi = rem / 14, pj = rem % 14;
    if ((border[img2][c][pi] >> pj) & 1u) {
      double best = -1e300;
      for (int dr = 0; dr < 2; ++dr)
        for (int dc = 0; dc < 2; ++dc) {
          double s = 0.0;
          const int cr = 2*pi + dr, cc = 2*pj + dc;
          for (int ic = 0; ic < 3; ++ic)
            for (int kr = 0; kr < 5; ++kr)
              for (int k = 0; k < 5; ++k)
                s += (double)ovl.img[IMG_IDX(img2*3 + ic, cr + kr, cc + k)] *
                     (double)wsm[c*84 + ic*28 + kr*5 + k];
          best = best > s ? best : s;
        }
      if (best + (double)sb1[c] >= 0.0) atomicOr(&bits1[img2][c][pi], 1u << pj);
    }
  }
  __syncthreads();

  // ---------- conv2 phase A: pack 30-bit input words per (i,j,kr) ----------
  for (int id = t; id < 1000; id += TPB) {
    const int img2 = id / 500;
    const int rem  = id % 500;
    const int kr = rem % 5;
    const int ij = rem / 5;
    const int i = ij / 10, j = ij % 10;
    uint32_t w = 0;
#pragma unroll
    for (int c = 0; c < 6; ++c)
      w |= ((bits1[img2][c][i + kr] >> j) & 31u) << (5*c);
    ovl.c2.ppatch[img2][i][j][kr] = w;
  }
  __syncthreads();

  // ---------- conv2 phase B: popcount diffs ----------
  for (int id = t; id < 3200; id += TPB) {
    const int img2 = id / 1600;
    const int rem  = id % 1600;
    const int oc = rem / 100;
    const int ij = rem % 100;
    const int i = ij / 10, j = ij % 10;
    int d = 0;
#pragma unroll
    for (int kr = 0; kr < 5; ++kr)
      d += __popc(ovl.c2.ppatch[img2][i][j][kr] ^ w2pks[oc][kr]);
    ovl.c2.dbuf[img2][oc][i][j] = (uint8_t)d;  // s = 150 - 2d
  }
  __syncthreads();

  // ---------- conv2 phase C: maxpool + bias + binarize ----------
  for (int id = t; id < 800; id += TPB) {
    const int img2 = id / 400;
    const int rem  = id % 400;
    const int oc  = rem / 25;
    const int pos = rem % 25;
    const int pi = pos / 5, pj = pos % 5;
    const uint8_t* dp = &ovl.c2.dbuf[img2][oc][2*pi][2*pj];
    int d0 = dp[0], d1 = dp[1], d2 = dp[10], d3 = dp[11];
    int dmin = min(min(d0, d1), min(d2, d3));
    float v = (float)(150 - 2*dmin) + b2[oc];
    if (v >= 0.f) atomicOr(&bits2[img2][pos], 1u << oc);
  }
  __syncthreads();

  // ---------- fc1 ----------
  for (int id = t; id < 240; id += TPB) {
    const int img2 = id / 120;
    const int o = id % 120;
    const uint32_t* wrow = wsu + WS_WF1P + o*25;
    int d = 0;
#pragma unroll
    for (int p = 0; p < 25; ++p) d += __popc(bits2[img2][p] ^ wrow[p]);
    float v = (float)(400 - 2*d) + bf1[o];
    if (v >= 0.f) atomicOr(&bitsf1[img2][o >> 5], 1u << (o & 31));
  }
  __syncthreads();

  // ---------- fc2 ----------
  for (int id = t; id < 168; id += TPB) {
    const int img2 = id / 84;
    const int o = id % 84;
    int d = 0;
#pragma unroll
    for (int q = 0; q < 4; ++q) d += __popc(bitsf1[img2][q] ^ wf2pks[o][q]);
    float v = (float)(120 - 2*d) + bf2[o];
    if (v >= 0.f) atomicOr(&bitsf2[img2][o >> 5], 1u << (o & 31));
  }
  __syncthreads();

  // ---------- fc3 ----------
  for (int id = t; id < 20; id += TPB) {
    const int img2 = id / 10;
    const int o = id % 10;
    int d = 0;
#pragma unroll
    for (int q = 0; q < 3; ++q) d += __popc(bitsf2[img2][q] ^ wf3pks[o][q]);
    out[(img0 + img2)*10 + o] = (float)(84 - 2*d) + bf3[o];
  }
}

extern "C" void kernel_launch(void* const* d_in, const int* in_sizes, int n_in,
                              void* d_out, int out_size, void* d_ws, size_t ws_size,
                              hipStream_t stream)
{
  const float* x   = (const float*)d_in[0];
  const float* w1  = (const float*)d_in[1];
  const float* b1  = (const float*)d_in[2];
  const float* w2  = (const float*)d_in[3];
  const float* b2  = (const float*)d_in[4];
  const float* wf1 = (const float*)d_in[5];
  const float* bf1 = (const float*)d_in[6];
  const float* wf2 = (const float*)d_in[7];
  const float* bf2 = (const float*)d_in[8];
  const float* wf3 = (const float*)d_in[9];
  const float* bf3 = (const float*)d_in[10];
  float*    wsf = (float*)d_ws;
  uint32_t* wsu = (uint32_t*)d_ws;

  hipLaunchKernelGGL(prep_kernel, dim3(16), dim3(TPB), 0, stream,
                     w1, w2, wf1, wf2, wf3, wsf, wsu);
  hipLaunchKernelGGL(lenet_kernel, dim3(4096), dim3(TPB), 0, stream,
                     x, b1, b2, bf1, bf2, bf3, wsf, wsu, (float*)d_out);
}

// Round 3
// 141.655 us; speedup vs baseline: 3.9572x; 1.4859x over previous
//
#include <hip/hip_runtime.h>
#include <stdint.h>

#define TPB 256

// d_ws layout (32-bit words from base)
#define WS_W1F   0      // 504 floats: binarized w1 as +/-1.0f, [6][3][28] (25 used per ic, 3 pad)
#define WS_W2PK  504    // 80 u32:  w2 bits, [16 oc][5 kr], bit (5c+k)
#define WS_WF1P  584    // 3000 u32: wf1 bits, [120 o][25 pos], bit oc
#define WS_WF2PK 3584   // 336 u32: wf2 bits, [84 o][4 q], bit = neuron q*32+b
#define WS_WF3PK 3920   // 30 u32:  wf3 bits, [10 o][3 q]

__global__ __launch_bounds__(TPB) void prep_kernel(
    const float* __restrict__ w1, const float* __restrict__ w2,
    const float* __restrict__ wf1, const float* __restrict__ wf2,
    const float* __restrict__ wf3, float* __restrict__ wsf,
    uint32_t* __restrict__ wsu)
{
  int id = blockIdx.x * TPB + threadIdx.x;
  if (id < 504) {
    int c = id / 84, r = id % 84, ic = r / 28, k = r % 28;
    wsf[WS_W1F + id] = (k < 25) ? ((w1[c*75 + ic*25 + k] >= 0.f) ? 1.f : -1.f) : 0.f;
  } else if (id < 584) {
    int r = id - 504, oc = r / 5, kr = r % 5;
    uint32_t w = 0;
    for (int c = 0; c < 6; ++c)
      for (int k = 0; k < 5; ++k)
        w |= (uint32_t)(w2[((oc*6 + c)*5 + kr)*5 + k] >= 0.f) << (5*c + k);
    wsu[WS_W2PK + r] = w;
  } else if (id < 3584) {
    int r = id - 584, o = r / 25, p = r % 25;
    uint32_t w = 0;
    for (int oc = 0; oc < 16; ++oc)
      w |= (uint32_t)(wf1[o*400 + oc*25 + p] >= 0.f) << oc;
    wsu[WS_WF1P + r] = w;
  } else if (id < 3920) {
    int r = id - 3584, o = r / 4, q = r % 4;
    uint32_t w = 0;
    for (int b = 0; b < 32; ++b) {
      int n = q*32 + b;
      if (n < 120) w |= (uint32_t)(wf2[o*120 + n] >= 0.f) << b;
    }
    wsu[WS_WF2PK + r] = w;
  } else if (id < 3950) {
    int r = id - 3920, o = r / 3, q = r % 3;
    uint32_t w = 0;
    for (int b = 0; b < 32; ++b) {
      int n = q*32 + b;
      if (n < 84) w |= (uint32_t)(wf3[o*84 + n] >= 0.f) << b;
    }
    wsu[WS_WF3PK + r] = w;
  }
}

// image plane layout: rows padded to 36 floats; 16B chunk index XOR'd with
// row-pair parity so the ~11 distinct window addresses per wave spread over
// 8 bank-starts (<=2 distinct addresses per bank => conflict-free per m136).
__device__ __forceinline__ int IMG_IDX(int plane, int row, int col) {
  int idx = plane * 1152 + row * 36 + col;
  return idx ^ (((row >> 1) & 1) << 2);
}

// Fused per-2-image pipeline: conv1(fp32) -> exact-sign resolve -> conv2(popcnt) -> fc1/2/3
__global__ __launch_bounds__(TPB, 4) void lenet_kernel(
    const float* __restrict__ x,
    const float* __restrict__ b1, const float* __restrict__ b2,
    const float* __restrict__ bf1, const float* __restrict__ bf2,
    const float* __restrict__ bf3,
    const float* __restrict__ wsf, const uint32_t* __restrict__ wsu,
    float* __restrict__ out)
{
  // image buffer overlaid with conv2 scratch (image is dead after resolve pass)
  __shared__ __align__(16) union Ovl {
    float img[6912];                                        // 2 img * 3 c * 32 rows * 36 = 27648 B
    struct { uint32_t ppatch[2][10][10][5]; uint32_t dbuf[2][16][100]; } c2; // 16800 B
  } ovl;
  __shared__ float wsm[504];             // binarized conv1 weights [6][3][28]
  __shared__ float sb1[6];
  __shared__ float sb2[16];
  __shared__ uint32_t bits1[2][6][14];   // pooled-binarized layer1: bit pj of pooled row pi
  __shared__ uint32_t border[2][6][14];  // borderline mask (needs exact fp64 arbitration)
  __shared__ uint32_t w2pks[16][5];
  __shared__ uint32_t bits2[2][25];      // bit oc per pooled pos
  __shared__ uint32_t wf2pks[84][4];
  __shared__ uint32_t wf3pks[10][3];
  __shared__ uint32_t bitsf1[2][4];
  __shared__ uint32_t bitsf2[2][3];

  const int t = threadIdx.x;
  const long long img0 = (long long)blockIdx.x * 2;

  // ---------- load phase ----------
  {
    const float4* src = (const float4*)(x + img0 * 3072);
#pragma unroll
    for (int k = 0; k < 6; ++k) {
      int id = k*TPB + t;              // 0..1535 : plane(6) x row(32) x f4col(8)
      int plane = id >> 8, rq = id & 255, row = rq >> 3, q = rq & 7;
      *(float4*)&ovl.img[IMG_IDX(plane, row, 4*q)] = src[id];
    }
    for (int id = t; id < 504; id += TPB) wsm[id] = wsf[WS_W1F + id];
    if (t < 6)  sb1[t] = b1[t];
    if (t >= 8 && t < 24) sb2[t-8] = b2[t-8];
    if (t < 80) w2pks[t/5][t%5] = wsu[WS_W2PK + t];
    if (t < 168) {
      ((uint32_t*)wf2pks)[t]       = wsu[WS_WF2PK + t];
      ((uint32_t*)wf2pks)[t + 168] = wsu[WS_WF2PK + t + 168];
      ((uint32_t*)bits1)[t]  = 0;
      ((uint32_t*)border)[t] = 0;
    }
    if (t < 30) ((uint32_t*)wf3pks)[t] = wsu[WS_WF3PK + t];
    if (t < 50) ((uint32_t*)bits2)[t] = 0;
    if (t < 8)  ((uint32_t*)bitsf1)[t] = 0;
    if (t < 6)  ((uint32_t*)bitsf2)[t] = 0;
  }
  __syncthreads();

  // ---------- conv1: fp32, c-broadcast lanes (6 lanes share one window),
  // ic-outer weight reload (28 live weight regs), 4 pooled cols per unit ----------
  {
    const int c   = t % 6;                 // fast index -> same-unit lanes broadcast LDS reads
    const int s0  = t / 6;
    const int nth = (c < 4) ? 43 : 42;
    const float bc = sb1[c];
    for (int s = s0; s < 112; s += nth) {  // 112 units: 2 img * 14 pi * 4 g
      const int img2 = s / 56;
      const int rem  = s % 56;
      const int pi = rem >> 2, g = rem & 3;
      const int colf = 8*g;
      float acc[2][8];
#pragma unroll
      for (int dr = 0; dr < 2; ++dr)
#pragma unroll
        for (int m = 0; m < 8; ++m) acc[dr][m] = 0.f;

#pragma unroll 1
      for (int ic = 0; ic < 3; ++ic) {
        float wr[28];
        const float4* wp = (const float4*)&wsm[c*84 + ic*28];
#pragma unroll
        for (int q2 = 0; q2 < 7; ++q2) {
          float4 v = wp[q2];
          wr[4*q2+0] = v.x; wr[4*q2+1] = v.y; wr[4*q2+2] = v.z; wr[4*q2+3] = v.w;
        }
        const int base = (img2*3 + ic)*1152 + 2*pi*36 + colf;
#pragma unroll
        for (int r = 0; r < 6; ++r) {
          const int idx = base + r*36;
          const int sw  = (((2*pi + r) >> 1) & 1) << 2;
          float xr[12];
          float4 v0 = *(const float4*)&ovl.img[(idx    ) ^ sw];
          float4 v1 = *(const float4*)&ovl.img[(idx + 4) ^ sw];
          float4 v2 = *(const float4*)&ovl.img[(idx + 8) ^ sw]; // g=3: row pad garbage -> only feeds discarded accs
          xr[0]=v0.x; xr[1]=v0.y; xr[2]=v0.z; xr[3]=v0.w;
          xr[4]=v1.x; xr[5]=v1.y; xr[6]=v1.z; xr[7]=v1.w;
          xr[8]=v2.x; xr[9]=v2.y; xr[10]=v2.z; xr[11]=v2.w;
#pragma unroll
          for (int dr = 0; dr < 2; ++dr) {
            const int kr = r - dr;
            if (kr < 0 || kr > 4) continue;   // compile-time pruned
#pragma unroll
            for (int k = 0; k < 5; ++k) {
              const float w = wr[kr*5 + k];
#pragma unroll
              for (int m = 0; m < 8; ++m)
                acc[dr][m] = fmaf(xr[m + k], w, acc[dr][m]);
            }
          }
        }
      }

      uint32_t nib = 0, nbord = 0;
#pragma unroll
      for (int jj = 0; jj < 4; ++jj) {
        const int pj = 4*g + jj;
        if (pj < 14) {                        // g=3: jj 2,3 discarded (garbage accs)
          float v = fmaxf(fmaxf(acc[0][2*jj], acc[0][2*jj+1]),
                          fmaxf(acc[1][2*jj], acc[1][2*jj+1]));
          float m = v + bc;
          if (fabsf(m) < 4e-3f)  nbord |= 1u << pj;   // fp32 worst-case err ~3e-4
          else if (m >= 0.f)     nib   |= 1u << pj;
        }
      }
      if (nib)   atomicOr(&bits1[img2][c][pi], nib);
      if (nbord) atomicOr(&border[img2][c][pi], nbord);
    }
  }
  __syncthreads();

  // ---------- borderline resolve: exact fp64 sign (rare) ----------
  for (int id = t; id < 2352; id += TPB) {  // 2 img * 6 c * 14 * 14
    const int img2 = id / 1176;
    int rem = id - img2*1176;
    const int c = rem / 196; rem -= c*196;
    const int pi = rem / 14, pj = rem % 14;
    if ((border[img2][c][pi] >> pj) & 1u) {
      double best = -1e300;
      for (int dr = 0; dr < 2; ++dr)
        for (int dc = 0; dc < 2; ++dc) {
          double s = 0.0;
          const int cr = 2*pi + dr, cc = 2*pj + dc;
          for (int ic = 0; ic < 3; ++ic)
            for (int kr = 0; kr < 5; ++kr)
              for (int k = 0; k < 5; ++k)
                s += (double)ovl.img[IMG_IDX(img2*3 + ic, cr + kr, cc + k)] *
                     (double)wsm[c*84 + ic*28 + kr*5 + k];
          best = best > s ? best : s;
        }
      if (best + (double)sb1[c] >= 0.0) atomicOr(&bits1[img2][c][pi], 1u << pj);
    }
  }
  __syncthreads();

  // ---------- conv2 phase A: pack 30-bit input words per (i,j,kr) ----------
  for (int id = t; id < 1000; id += TPB) {
    const int img2 = id / 500;
    const int rem  = id % 500;
    const int kr = rem % 5;
    const int ij = rem / 5;
    const int i = ij / 10, j = ij % 10;
    uint32_t w = 0;
#pragma unroll
    for (int c = 0; c < 6; ++c)
      w |= ((bits1[img2][c][i + kr] >> j) & 31u) << (5*c);
    ovl.c2.ppatch[img2][i][j][kr] = w;
  }
  __syncthreads();

  // ---------- conv2 phase B: popcount diffs (u32 dbuf: no sub-word write serialization) ----------
  for (int id = t; id < 3200; id += TPB) {
    const int img2 = id / 1600;
    const int rem  = id % 1600;
    const int oc = rem / 100;
    const int ij = rem % 100;
    int d = 0;
#pragma unroll
    for (int kr = 0; kr < 5; ++kr)
      d += __popc(ovl.c2.ppatch[img2][ij/10][ij%10][kr] ^ w2pks[oc][kr]);
    ovl.c2.dbuf[img2][oc][ij] = (uint32_t)d;  // s = 150 - 2d
  }
  __syncthreads();

  // ---------- conv2 phase C: maxpool + bias + binarize ----------
  for (int id = t; id < 800; id += TPB) {
    const int img2 = id / 400;
    const int rem  = id % 400;
    const int oc  = rem / 25;
    const int pos = rem % 25;
    const int pi = pos / 5, pj = pos % 5;
    const uint32_t* dp = &ovl.c2.dbuf[img2][oc][20*pi + 2*pj];
    uint32_t d0 = dp[0], d1 = dp[1], d2 = dp[10], d3 = dp[11];
    int dmin = (int)min(min(d0, d1), min(d2, d3));
    float v = (float)(150 - 2*dmin) + sb2[oc];
    if (v >= 0.f) atomicOr(&bits2[img2][pos], 1u << oc);
  }
  __syncthreads();

  // ---------- fc1 ----------
  for (int id = t; id < 240; id += TPB) {
    const int img2 = id / 120;
    const int o = id % 120;
    const uint32_t* wrow = wsu + WS_WF1P + o*25;
    int d = 0;
#pragma unroll
    for (int p = 0; p < 25; ++p) d += __popc(bits2[img2][p] ^ wrow[p]);
    float v = (float)(400 - 2*d) + bf1[o];
    if (v >= 0.f) atomicOr(&bitsf1[img2][o >> 5], 1u << (o & 31));
  }
  __syncthreads();

  // ---------- fc2 ----------
  for (int id = t; id < 168; id += TPB) {
    const int img2 = id / 84;
    const int o = id % 84;
    int d = 0;
#pragma unroll
    for (int q = 0; q < 4; ++q) d += __popc(bitsf1[img2][q] ^ wf2pks[o][q]);
    float v = (float)(120 - 2*d) + bf2[o];
    if (v >= 0.f) atomicOr(&bitsf2[img2][o >> 5], 1u << (o & 31));
  }
  __syncthreads();

  // ---------- fc3 ----------
  for (int id = t; id < 20; id += TPB) {
    const int img2 = id / 10;
    const int o = id % 10;
    int d = 0;
#pragma unroll
    for (int q = 0; q < 3; ++q) d += __popc(bitsf2[img2][q] ^ wf3pks[o][q]);
    out[(img0 + img2)*10 + o] = (float)(84 - 2*d) + bf3[o];
  }
}

extern "C" void kernel_launch(void* const* d_in, const int* in_sizes, int n_in,
                              void* d_out, int out_size, void* d_ws, size_t ws_size,
                              hipStream_t stream)
{
  const float* x   = (const float*)d_in[0];
  const float* w1  = (const float*)d_in[1];
  const float* b1  = (const float*)d_in[2];
  const float* w2  = (const float*)d_in[3];
  const float* b2  = (const float*)d_in[4];
  const float* wf1 = (const float*)d_in[5];
  const float* bf1 = (const float*)d_in[6];
  const float* wf2 = (const float*)d_in[7];
  const float* bf2 = (const float*)d_in[8];
  const float* wf3 = (const float*)d_in[9];
  const float* bf3 = (const float*)d_in[10];
  float*    wsf = (float*)d_ws;
  uint32_t* wsu = (uint32_t*)d_ws;

  hipLaunchKernelGGL(prep_kernel, dim3(16), dim3(TPB), 0, stream,
                     w1, w2, wf1, wf2, wf3, wsf, wsu);
  hipLaunchKernelGGL(lenet_kernel, dim3(4096), dim3(TPB), 0, stream,
                     x, b1, b2, bf1, bf2, bf3, wsf, wsu, (float*)d_out);
}